// Round 1
// baseline (707.678 us; speedup 1.0000x reference)
//
#include <hip/hip_runtime.h>
#include <hip/hip_bf16.h>

#define N 1024
#define D 128
#define SB 32          // steps per superstep (gi chunk staged in LDS)
#define NSB (N / SB)

typedef __hip_bfloat16 bf16;
typedef __attribute__((ext_vector_type(8))) short bfx8;    // 8 bf16 (4 VGPRs) MFMA A/B frag
typedef __attribute__((ext_vector_type(4))) float fx4;     // MFMA C/D frag
typedef __attribute__((ext_vector_type(8))) unsigned short u16x8;

__device__ __forceinline__ float b2f(bf16 x) { return __bfloat162float(x); }
__device__ __forceinline__ short f2bf_bits(float x) {
    bf16 b = __float2bfloat16(x);
    return *reinterpret_cast<short*>(&b);
}
__device__ __forceinline__ float bfbits2f(unsigned short u) {
    return __uint_as_float(((unsigned int)u) << 16);
}
__device__ __forceinline__ float fastrcp(float x) { return __builtin_amdgcn_rcpf(x); }

__device__ __forceinline__ float fast_tanh(float x) {
    float e = __expf(2.f * x);
    return 1.f - 2.f * fastrcp(e + 1.f);
}
__device__ __forceinline__ float fast_sigmoid(float x) {
    return fastrcp(1.f + __expf(-x));
}

// dynamic extract from fx4 by r (3 cndmask)
__device__ __forceinline__ float sel4(fx4 v, int r) {
    float x = (r & 1) ? v[1] : v[0];
    float y = (r & 1) ? v[3] : v[2];
    return (r & 2) ? y : x;
}

// async 16B global->LDS (lds base wave-uniform; HW scatters lane i at base+i*16)
__device__ __forceinline__ void async_copy16(const float* g, void* l) {
    __builtin_amdgcn_global_load_lds((const __attribute__((address_space(1))) void*)g,
                                     (__attribute__((address_space(3))) void*)l, 16, 0, 0);
}

// consumer-side: wait until all SB rows of superstep sb are published (agent-scope acquire)
__device__ __forceinline__ void wait_rows(int* cnt, int sb) {
    while (__hip_atomic_load(&cnt[sb], __ATOMIC_ACQUIRE, __HIP_MEMORY_SCOPE_AGENT) < SB)
        __builtin_amdgcn_s_sleep(2);
}

#define MFMA(A, B, C) __builtin_amdgcn_mfma_f32_16x16x32_bf16((A), (B), (C), 0, 0, 0)

// ---------------- K0a: dtype sniff + producer/consumer counter clear ----------------
__global__ void sniff_kernel(const unsigned short* __restrict__ xu, int* __restrict__ flag,
                             int* __restrict__ cnt) {
    int l = threadIdx.x;  // 64 threads
    if (l < NSB) cnt[l] = 0;
    int c = 0;
#pragma unroll
    for (int k = 0; k < 8; ++k) {
        unsigned short u = xu[2 * (l * 8 + k)];
        int e = (u >> 7) & 0xFF;
        c += (e >= 96 && e <= 144) ? 1 : 0;
    }
    for (int off = 32; off > 0; off >>= 1) c += __shfl_down(c, off);
    if (l == 0) *flag = (c > 400) ? 1 : 0;
}

// ---------------- K0b: convert all inputs to fp32 in ws ----------------
struct ConvArgs {
    const void* p[8];
    float* o[8];
    int n[8];
};
__global__ void convert_kernel(ConvArgs A, const int* __restrict__ flag) {
    int seg = blockIdx.y;
    int n = A.n[seg];
    int isbf = *flag;
    const void* p = A.p[seg];
    float* o = A.o[seg];
    for (int i = blockIdx.x * blockDim.x + threadIdx.x; i < n; i += gridDim.x * blockDim.x) {
        float v = isbf ? b2f(((const bf16*)p)[i]) : ((const float*)p)[i];
        o[i] = v;
    }
}

// ---------------- K0c: w_ihT[c][o] = w_ih[o][c]  (coalesced write) ----------------
__global__ void transpose_wih(const float* __restrict__ wih, float* __restrict__ wihT) {
    int id = blockIdx.x * 256 + threadIdx.x;   // 98304 total
    int c = id / 384;
    int o = id - c * 384;
    wihT[id] = wih[o * 256 + c];               // read stride 1KB (L2), write coalesced
}

// ---------------- K1: q = X@Wq^T, kT = (X@Wk^T)^T ----------------
__global__ void qk_kernel(const float* __restrict__ X, const float* __restrict__ Wq,
                          const float* __restrict__ Wk,
                          float* __restrict__ q, float* __restrict__ kT) {
    int i = blockIdx.x & (N - 1);
    bool is_k = blockIdx.x >= N;
    int d = threadIdx.x;  // 0..127
    const float* W = is_k ? Wk : Wq;
    float acc = 0.f;
#pragma unroll 8
    for (int c = 0; c < D; ++c)
        acc += X[i * D + c] * W[d * D + c];
    if (is_k) kT[d * N + i] = acc;
    else      q[i * D + d] = acc;
}

// ---------------- K2: fused  attn rows (blocks 1..N)  ||  GRU (block 0) ----------------
// attn block i = blockIdx-1: scores+softmax+att+gi row i, then fence + release-add cnt[i/32].
// gru block 0: polls cnt[sb] (acquire) before prefetching superstep sb's gi chunk.
// LDS is a manual union: gru needs 106752 B (gi double-buffer + hist), attn needs 7168 B.
__global__ void __launch_bounds__(256, 1) fused_kernel(
        const float* __restrict__ q, const float* __restrict__ kT,
        const float* __restrict__ v, const float* __restrict__ X,
        const float* __restrict__ wihT, const float* __restrict__ b_ih,
        float* __restrict__ gi,
        const float* __restrict__ w_hh, const float* __restrict__ b_hh,
        void* __restrict__ out, const int* __restrict__ flag,
        int* __restrict__ cnt) {
    __shared__ __align__(16) char smem[2 * SB * 3 * D * 4 + (SB + 1) * D * 2];  // 106752 B
    int t = threadIdx.x;

    if (blockIdx.x != 0) {
        // =================== attention row ===================
        int i = blockIdx.x - 1;
        float* qs   = (float*)smem;        // D
        float* vs   = qs + D;              // D
        float* xr   = vs + D;              // D
        float* al   = xr + D;              // D
        float* wrow = al + D;              // N
        float* red  = wrow + N;            // 256

        if (t < D) { qs[t] = q[i * D + t]; vs[t] = v[t]; xr[t] = X[i * D + t]; }
        __syncthreads();

        float sj[4];
        int nj = 0;
        float m = -1e30f;
        for (int j = i + t; j < N; j += 256) {
            float s = 0.f;
#pragma unroll 8
            for (int d = 0; d < D; ++d) s += vs[d] * fast_tanh(qs[d] + kT[d * N + j]);
            sj[nj++] = s;
            m = fmaxf(m, s);
        }
        red[t] = m;
        __syncthreads();
        for (int st = 128; st > 0; st >>= 1) {
            if (t < st) red[t] = fmaxf(red[t], red[t + st]);
            __syncthreads();
        }
        m = red[0];
        __syncthreads();
        float lsum = 0.f;
        {
            int it = 0;
            for (int j = i + t; j < N; j += 256, ++it) {
                float p = __expf(sj[it] - m);
                wrow[j] = p;
                lsum += p;
            }
        }
        red[t] = lsum;
        __syncthreads();
        for (int st = 128; st > 0; st >>= 1) {
            if (t < st) red[t] += red[t + st];
            __syncthreads();
        }
        float inv = fastrcp(red[0]);
        __syncthreads();   // protect red[0] before reuse below

        // Phase C
        int d = t & 127, half = t >> 7;
        float acc = 0.f;
        for (int j = i + half; j < N; j += 2) acc += wrow[j] * X[j * D + d];
        if (half) red[d] = acc;
        __syncthreads();
        if (!half) al[d] = (acc + red[d]) * inv;
        __syncthreads();

        // Phase D
        for (int o = t; o < 3 * D; o += 256) {
            float a2 = b_ih[o];
            const float* wt = wihT + o;
#pragma unroll 8
            for (int c = 0; c < D; ++c) a2 += xr[c] * wt[c * 384];
#pragma unroll 8
            for (int c = 0; c < D; ++c) a2 += al[c] * wt[(D + c) * 384];
            gi[i * 3 * D + o] = a2;
        }
        __syncthreads();
        if (t == 0) {
            __threadfence();  // make this block's gi stores device-visible
            __hip_atomic_fetch_add(&cnt[i >> 5], 1, __ATOMIC_RELEASE, __HIP_MEMORY_SCOPE_AGENT);
        }
        return;
    }

    // =================== GRU (1 block, serial over N steps) ===================
    float* gi_lds = (float*)smem;                           // [2][SB][3D]
    short* hist   = (short*)(smem + 2 * SB * 3 * D * 4);    // [SB+1][D]
    int w = t >> 6;
    int l = t & 63;
    int qq = l >> 4;
    int nn = l & 15;
    int isbf = *flag;

    // A-frags: a[tau][mqi][kc]; A[m=nn][k=32kc+8q+j]
    bfx8 a[3][2][4];
#pragma unroll
    for (int tau = 0; tau < 3; ++tau)
#pragma unroll
        for (int mqi = 0; mqi < 2; ++mqi)
#pragma unroll
            for (int kc = 0; kc < 4; ++kc) {
                int row = 128 * tau + 16 * (2 * w + mqi) + nn;
                int k0 = 32 * kc + 8 * qq;
#pragma unroll
                for (int j = 0; j < 8; ++j)
                    a[tau][mqi][kc][j] = f2bf_bits(w_hh[row * D + k0 + j]);
            }
    // bias C-init frags: C row = 4q + r of tile (tau, 2w+mqi)
    fx4 bias[3][2];
#pragma unroll
    for (int tau = 0; tau < 3; ++tau)
#pragma unroll
        for (int mqi = 0; mqi < 2; ++mqi)
#pragma unroll
            for (int r = 0; r < 4; ++r)
                bias[tau][mqi][r] = b_hh[128 * tau + 16 * (2 * w + mqi) + 4 * qq + r];

    int rsel = l & 3;
    int mqsel = (l >> 3) & 1;
    int drow = 32 * w + 16 * mqsel + 4 * qq + rsel;
    float h = 0.f;

    int fr = 1 + (t >> 3);
    int fc = (t & 7) * 16;

    // wait for superstep 0's rows, then prefetch
    wait_rows(cnt, 0);
    {
        const float* src = gi;
        for (int mm = 0; mm < 12; ++mm) {
            int off = (w * 12 + mm) * 256;
            async_copy16(src + off + (l << 2), smem + off * 4);
        }
    }

    for (int sb = 0; sb < NSB; ++sb) {
        int cb = sb & 1;
        u16x8 h0 = 0, h1 = 0;
        int hcopy = 0;
        if (sb > 0) {
            h0 = *(const u16x8*)(hist + fr * D + fc);
            h1 = *(const u16x8*)(hist + fr * D + fc + 8);
            if (t < 64) hcopy = ((const int*)(hist + SB * D))[t];
        }
        // prefetch sb+1 FIRST (so the counted vmcnt below can leave stores in flight)
        if (sb + 1 < NSB) {
            wait_rows(cnt, sb + 1);
            const float* src = gi + (size_t)(sb + 1) * SB * 3 * D;
            char* dst = smem + (cb ^ 1) * SB * 3 * D * 4;
            for (int mm = 0; mm < 12; ++mm) {
                int off = (w * 12 + mm) * 256;
                async_copy16(src + off + (l << 2), dst + off * 4);
            }
        }
        // output stores for superstep sb-1 (values already in regs; never need draining)
        if (sb > 0) {
            int orow = (sb - 1) * SB + fr - 1;
            if (isbf) {
                *(u16x8*)((unsigned short*)out + orow * D + fc) = h0;
                *(u16x8*)((unsigned short*)out + orow * D + fc + 8) = h1;
            } else {
                float* op = (float*)out + orow * D + fc;
                fx4 f0, f1, f2, f3;
#pragma unroll
                for (int j = 0; j < 4; ++j) {
                    f0[j] = bfbits2f(h0[j]);     f1[j] = bfbits2f(h0[4 + j]);
                    f2[j] = bfbits2f(h1[j]);     f3[j] = bfbits2f(h1[4 + j]);
                }
                *(fx4*)op = f0; *(fx4*)(op + 4) = f1;
                *(fx4*)(op + 8) = f2; *(fx4*)(op + 12) = f3;
            }
        }
        if (t < 64) ((int*)hist)[t] = (sb == 0) ? 0 : hcopy;

        // Counted vmcnt: in-order retirement means "<=K outstanding" with K <= (#ops newer
        // than this superstep's prefetch) guarantees that prefetch is complete.
        // sb==0: newer = prefetch1(12)          -> vmcnt(12)
        // mid:   newer = st(ns)+pf(12)+st(ns)>=16 -> vmcnt(16)   (ns=2 bf16 / 4 f32)
        // last:  newer = 2*ns >= 4              -> vmcnt(4)
        if (sb == 0)
            asm volatile("s_waitcnt vmcnt(12) lgkmcnt(0)\ns_barrier" ::: "memory");
        else if (sb + 1 < NSB)
            asm volatile("s_waitcnt vmcnt(16) lgkmcnt(0)\ns_barrier" ::: "memory");
        else
            asm volatile("s_waitcnt vmcnt(4) lgkmcnt(0)\ns_barrier" ::: "memory");

        // running pointers for the inner loop
        const char* hrd = (const char*)hist + 16 * qq;            // step +256 B (one row)
        const float* gp = gi_lds + cb * SB * 3 * D + drow;        // step +384 floats
        short* hwr = hist + D + drow;                             // step +128 shorts

        for (int s = 0; s < SB; ++s) {
            bfx8 b0 = *(const bfx8*)(hrd);
            bfx8 b1 = *(const bfx8*)(hrd + 64);
            bfx8 b2 = *(const bfx8*)(hrd + 128);
            bfx8 b3 = *(const bfx8*)(hrd + 192);
            float gr = gp[0];
            float gz = gp[D];
            float gn = gp[2 * D];

            // r-gate chains first: sigmoid(r) overlaps the z/n MFMA chains (r is on n's path)
            fx4 c00 = bias[0][0], c01 = bias[0][1];
            c00 = MFMA(a[0][0][0], b0, c00); c00 = MFMA(a[0][0][1], b1, c00);
            c00 = MFMA(a[0][0][2], b2, c00); c00 = MFMA(a[0][0][3], b3, c00);
            c01 = MFMA(a[0][1][0], b0, c01); c01 = MFMA(a[0][1][1], b1, c01);
            c01 = MFMA(a[0][1][2], b2, c01); c01 = MFMA(a[0][1][3], b3, c01);
            float ar = sel4(mqsel ? c01 : c00, rsel);
            float rr = fast_sigmoid(gr + ar);

            fx4 c20 = bias[2][0], c21 = bias[2][1];
            c20 = MFMA(a[2][0][0], b0, c20); c20 = MFMA(a[2][0][1], b1, c20);
            c20 = MFMA(a[2][0][2], b2, c20); c20 = MFMA(a[2][0][3], b3, c20);
            c21 = MFMA(a[2][1][0], b0, c21); c21 = MFMA(a[2][1][1], b1, c21);
            c21 = MFMA(a[2][1][2], b2, c21); c21 = MFMA(a[2][1][3], b3, c21);
            float an = sel4(mqsel ? c21 : c20, rsel);

            fx4 c10 = bias[1][0], c11 = bias[1][1];
            c10 = MFMA(a[1][0][0], b0, c10); c10 = MFMA(a[1][0][1], b1, c10);
            c10 = MFMA(a[1][0][2], b2, c10); c10 = MFMA(a[1][0][3], b3, c10);
            c11 = MFMA(a[1][1][0], b0, c11); c11 = MFMA(a[1][1][1], b1, c11);
            c11 = MFMA(a[1][1][2], b2, c11); c11 = MFMA(a[1][1][3], b3, c11);
            float az = sel4(mqsel ? c11 : c10, rsel);

            float zz = fast_sigmoid(gz + az);
            float nst = fast_tanh(gn + rr * an);
            h = (1.f - zz) * nst + zz * h;
            *hwr = f2bf_bits(h);     // 2 replica lanes, same addr+data: free

            hrd += 256;
            gp += 3 * D;
            hwr += D;
            asm volatile("s_waitcnt lgkmcnt(0)\ns_barrier" ::: "memory");
        }
    }
    // final flush
    {
        u16x8 h0 = *(const u16x8*)(hist + fr * D + fc);
        u16x8 h1 = *(const u16x8*)(hist + fr * D + fc + 8);
        int orow = (NSB - 1) * SB + fr - 1;
        if (isbf) {
            *(u16x8*)((unsigned short*)out + orow * D + fc) = h0;
            *(u16x8*)((unsigned short*)out + orow * D + fc + 8) = h1;
        } else {
            float* op = (float*)out + orow * D + fc;
            fx4 f0, f1, f2, f3;
#pragma unroll
            for (int j = 0; j < 4; ++j) {
                f0[j] = bfbits2f(h0[j]);     f1[j] = bfbits2f(h0[4 + j]);
                f2[j] = bfbits2f(h1[j]);     f3[j] = bfbits2f(h1[4 + j]);
            }
            *(fx4*)op = f0; *(fx4*)(op + 4) = f1;
            *(fx4*)(op + 8) = f2; *(fx4*)(op + 12) = f3;
        }
    }
}

extern "C" void kernel_launch(void* const* d_in, const int* in_sizes, int n_in,
                              void* d_out, int out_size, void* d_ws, size_t ws_size,
                              hipStream_t stream) {
    (void)in_sizes; (void)n_in; (void)out_size; (void)ws_size;

    float* w0 = (float*)d_ws;
    int*   flag = (int*)w0;                 // w0[0]
    int*   cnt  = (int*)w0 + 16;            // w0[16..48): per-superstep row counters
    float* Xf   = w0 + 64;
    float* Wqf  = Xf   + N * D;
    float* Wkf  = Wqf  + D * D;
    float* vf   = Wkf  + D * D;
    float* wihf = vf   + D;
    float* whhf = wihf + 3 * D * 2 * D;
    float* bihf = whhf + 3 * D * D;
    float* bhhf = bihf + 3 * D;
    float* q    = bhhf + 3 * D;
    float* kT   = q    + N * D;
    float* wihT = kT   + N * D;             // 3D x 2D transposed
    float* gi   = wihT + 3 * D * 2 * D;     // N x 3D

    sniff_kernel<<<1, 64, 0, stream>>>((const unsigned short*)d_in[0], flag, cnt);

    ConvArgs A;
    A.p[0] = d_in[0]; A.o[0] = Xf;   A.n[0] = N * D;
    A.p[1] = d_in[1]; A.o[1] = Wqf;  A.n[1] = D * D;
    A.p[2] = d_in[2]; A.o[2] = Wkf;  A.n[2] = D * D;
    A.p[3] = d_in[3]; A.o[3] = vf;   A.n[3] = D;
    A.p[4] = d_in[4]; A.o[4] = wihf; A.n[4] = 3 * D * 2 * D;
    A.p[5] = d_in[5]; A.o[5] = whhf; A.n[5] = 3 * D * D;
    A.p[6] = d_in[6]; A.o[6] = bihf; A.n[6] = 3 * D;
    A.p[7] = d_in[7]; A.o[7] = bhhf; A.n[7] = 3 * D;
    dim3 cgrid(128, 8, 1);
    convert_kernel<<<cgrid, 256, 0, stream>>>(A, flag);

    transpose_wih<<<(3 * D * 2 * D) / 256, 256, 0, stream>>>(wihf, wihT);
    qk_kernel<<<2 * N, D, 0, stream>>>(Xf, Wqf, Wkf, q, kT);
    fused_kernel<<<N + 1, 256, 0, stream>>>(q, kT, vf, Xf, wihT, bihf, gi,
                                            whhf, bhhf, d_out, flag, cnt);
}

// Round 2
// 694.330 us; speedup vs baseline: 1.0192x; 1.0192x over previous
//
#include <hip/hip_runtime.h>
#include <hip/hip_bf16.h>

#define N 1024
#define D 128
#define SB 32          // steps per superstep (gi chunk staged in LDS)
#define NSB (N / SB)

typedef __hip_bfloat16 bf16;
typedef __attribute__((ext_vector_type(8))) short bfx8;    // 8 bf16 (4 VGPRs) MFMA A/B frag
typedef __attribute__((ext_vector_type(4))) float fx4;     // MFMA C/D frag
typedef __attribute__((ext_vector_type(8))) unsigned short u16x8;

__device__ __forceinline__ float b2f(bf16 x) { return __bfloat162float(x); }
__device__ __forceinline__ short f2bf_bits(float x) {
    bf16 b = __float2bfloat16(x);
    return *reinterpret_cast<short*>(&b);
}
__device__ __forceinline__ float bfbits2f(unsigned short u) {
    return __uint_as_float(((unsigned int)u) << 16);
}
__device__ __forceinline__ float fastrcp(float x) { return __builtin_amdgcn_rcpf(x); }

__device__ __forceinline__ float fast_tanh(float x) {
    float e = __expf(2.f * x);
    return 1.f - 2.f * fastrcp(e + 1.f);
}
__device__ __forceinline__ float fast_sigmoid(float x) {
    return fastrcp(1.f + __expf(-x));
}

// dynamic extract from fx4 by r (3 cndmask)
__device__ __forceinline__ float sel4(fx4 v, int r) {
    float x = (r & 1) ? v[1] : v[0];
    float y = (r & 1) ? v[3] : v[2];
    return (r & 2) ? y : x;
}

// async 16B global->LDS (lds base wave-uniform; HW scatters lane i at base+i*16)
__device__ __forceinline__ void async_copy16(const float* g, void* l) {
    __builtin_amdgcn_global_load_lds((const __attribute__((address_space(1))) void*)g,
                                     (__attribute__((address_space(3))) void*)l, 16, 0, 0);
}

// consumer-side: wait until all SB rows of superstep sb are published (agent-scope acquire)
__device__ __forceinline__ void wait_rows(int* cnt, int sb) {
    while (__hip_atomic_load(&cnt[sb], __ATOMIC_ACQUIRE, __HIP_MEMORY_SCOPE_AGENT) < SB)
        __builtin_amdgcn_s_sleep(2);
}

#define MFMA(A, B, C) __builtin_amdgcn_mfma_f32_16x16x32_bf16((A), (B), (C), 0, 0, 0)

// ---------------- K0a: dtype sniff + producer/consumer counter clear ----------------
__global__ void sniff_kernel(const unsigned short* __restrict__ xu, int* __restrict__ flag,
                             int* __restrict__ cnt) {
    int l = threadIdx.x;  // 64 threads
    if (l < NSB) cnt[l] = 0;
    int c = 0;
#pragma unroll
    for (int k = 0; k < 8; ++k) {
        unsigned short u = xu[2 * (l * 8 + k)];
        int e = (u >> 7) & 0xFF;
        c += (e >= 96 && e <= 144) ? 1 : 0;
    }
    for (int off = 32; off > 0; off >>= 1) c += __shfl_down(c, off);
    if (l == 0) *flag = (c > 400) ? 1 : 0;
}

// ---------------- K0b: convert all inputs to fp32 in ws ----------------
struct ConvArgs {
    const void* p[8];
    float* o[8];
    int n[8];
};
__global__ void convert_kernel(ConvArgs A, const int* __restrict__ flag) {
    int seg = blockIdx.y;
    int n = A.n[seg];
    int isbf = *flag;
    const void* p = A.p[seg];
    float* o = A.o[seg];
    for (int i = blockIdx.x * blockDim.x + threadIdx.x; i < n; i += gridDim.x * blockDim.x) {
        float v = isbf ? b2f(((const bf16*)p)[i]) : ((const float*)p)[i];
        o[i] = v;
    }
}

// ---------------- K0c: transposes (coalesced writes): wihT, WqT, WkT ----------------
__global__ void transpose_all(const float* __restrict__ wih, float* __restrict__ wihT,
                              const float* __restrict__ Wq, float* __restrict__ WqT,
                              const float* __restrict__ Wk, float* __restrict__ WkT) {
    int id = blockIdx.x * 256 + threadIdx.x;   // 131072 total
    if (id < 98304) {
        int c = id / 384, o = id - c * 384;
        wihT[id] = wih[o * 256 + c];           // read stride 1KB (L2), write coalesced
    } else if (id < 98304 + 16384) {
        int k = id - 98304;
        int c = k >> 7, d = k & 127;
        WqT[k] = Wq[d * 128 + c];
    } else {
        int k = id - 114688;
        int c = k >> 7, d = k & 127;
        WkT[k] = Wk[d * 128 + c];
    }
}

// ---------------- K1: q = X@Wq^T, kT = (X@Wk^T)^T, coalesced via WT ----------------
// block i: t<128 computes q[i,:], t>=128 computes k[i,:] -> kT[:,i]. X row in LDS.
__global__ void qk_kernel(const float* __restrict__ X, const float* __restrict__ WqT,
                          const float* __restrict__ WkT,
                          float* __restrict__ q, float* __restrict__ kT) {
    int i = blockIdx.x;
    int t = threadIdx.x;
    int d = t & 127;
    __shared__ float xs[D];
    if (t < D) xs[t] = X[i * D + t];
    __syncthreads();
    const float* WT = (t < 128) ? WqT : WkT;
    float acc = 0.f;
#pragma unroll 8
    for (int c = 0; c < D; ++c)
        acc += xs[c] * WT[c * D + d];          // WT read coalesced across lanes
    if (t < 128) q[i * D + d] = acc;
    else         kT[d * N + i] = acc;
}

// ---------------- K2: fused  attn rows (blocks 1..N)  ||  GRU (block 0) ----------------
// attn block i = blockIdx-1: scores+softmax+att+gi row i, then fence + release-add cnt[i/32].
// gru block 0: polls cnt[sb] (acquire) before prefetching superstep sb's gi chunk.
// LDS is a manual union: gru needs 106752 B (gi double-buffer + hist), attn needs 7168 B.
__global__ void __launch_bounds__(256, 1) fused_kernel(
        const float* __restrict__ q, const float* __restrict__ kT,
        const float* __restrict__ v, const float* __restrict__ X,
        const float* __restrict__ wihT, const float* __restrict__ b_ih,
        float* __restrict__ gi,
        const float* __restrict__ w_hh, const float* __restrict__ b_hh,
        void* __restrict__ out, const int* __restrict__ flag,
        int* __restrict__ cnt) {
    __shared__ __align__(16) char smem[2 * SB * 3 * D * 4 + (SB + 1) * D * 2];  // 106752 B
    int t = threadIdx.x;

    if (blockIdx.x != 0) {
        // =================== attention row ===================
        int i = blockIdx.x - 1;
        float* qs   = (float*)smem;        // D
        float* vs   = qs + D;              // D
        float* xr   = vs + D;              // D
        float* al   = xr + D;              // D
        float* wrow = al + D;              // N
        float* red  = wrow + N;            // 256

        if (t < D) { qs[t] = q[i * D + t]; vs[t] = v[t]; xr[t] = X[i * D + t]; }
        __syncthreads();

        float sj[4];
        int nj = 0;
        float m = -1e30f;
        for (int j = i + t; j < N; j += 256) {
            float s = 0.f;
#pragma unroll 8
            for (int d = 0; d < D; ++d) s += vs[d] * fast_tanh(qs[d] + kT[d * N + j]);
            sj[nj++] = s;
            m = fmaxf(m, s);
        }
        red[t] = m;
        __syncthreads();
        for (int st = 128; st > 0; st >>= 1) {
            if (t < st) red[t] = fmaxf(red[t], red[t + st]);
            __syncthreads();
        }
        m = red[0];
        __syncthreads();
        float lsum = 0.f;
        {
            int it = 0;
            for (int j = i + t; j < N; j += 256, ++it) {
                float p = __expf(sj[it] - m);
                wrow[j] = p;
                lsum += p;
            }
        }
        red[t] = lsum;
        __syncthreads();
        for (int st = 128; st > 0; st >>= 1) {
            if (t < st) red[t] += red[t + st];
            __syncthreads();
        }
        float inv = fastrcp(red[0]);
        __syncthreads();   // protect red[0] before reuse below

        // Phase C
        int d = t & 127, half = t >> 7;
        float acc = 0.f;
        for (int j = i + half; j < N; j += 2) acc += wrow[j] * X[j * D + d];
        if (half) red[d] = acc;
        __syncthreads();
        if (!half) al[d] = (acc + red[d]) * inv;
        __syncthreads();

        // Phase D
        for (int o = t; o < 3 * D; o += 256) {
            float a2 = b_ih[o];
            const float* wt = wihT + o;
#pragma unroll 8
            for (int c = 0; c < D; ++c) a2 += xr[c] * wt[c * 384];
#pragma unroll 8
            for (int c = 0; c < D; ++c) a2 += al[c] * wt[(D + c) * 384];
            gi[i * 3 * D + o] = a2;
        }
        __syncthreads();
        if (t == 0) {
            __threadfence();  // make this block's gi stores device-visible
            __hip_atomic_fetch_add(&cnt[i >> 5], 1, __ATOMIC_RELEASE, __HIP_MEMORY_SCOPE_AGENT);
        }
        return;
    }

    // =================== GRU (1 block, serial over N steps) ===================
    float* gi_lds = (float*)smem;                           // [2][SB][3D]
    short* hist   = (short*)(smem + 2 * SB * 3 * D * 4);    // [SB+1][D]
    int w = t >> 6;
    int l = t & 63;
    int qq = l >> 4;
    int nn = l & 15;
    int isbf = *flag;

    // A-frags: a[tau][mqi][kc]; A[m=nn][k=32kc+8q+j]
    bfx8 a[3][2][4];
#pragma unroll
    for (int tau = 0; tau < 3; ++tau)
#pragma unroll
        for (int mqi = 0; mqi < 2; ++mqi)
#pragma unroll
            for (int kc = 0; kc < 4; ++kc) {
                int row = 128 * tau + 16 * (2 * w + mqi) + nn;
                int k0 = 32 * kc + 8 * qq;
#pragma unroll
                for (int j = 0; j < 8; ++j)
                    a[tau][mqi][kc][j] = f2bf_bits(w_hh[row * D + k0 + j]);
            }
    // bias C-init frags: C row = 4q + r of tile (tau, 2w+mqi)
    fx4 bias[3][2];
#pragma unroll
    for (int tau = 0; tau < 3; ++tau)
#pragma unroll
        for (int mqi = 0; mqi < 2; ++mqi)
#pragma unroll
            for (int r = 0; r < 4; ++r)
                bias[tau][mqi][r] = b_hh[128 * tau + 16 * (2 * w + mqi) + 4 * qq + r];

    int rsel = l & 3;
    int mqsel = (l >> 3) & 1;
    int drow = 32 * w + 16 * mqsel + 4 * qq + rsel;
    float h = 0.f;

    int fr = 1 + (t >> 3);
    int fc = (t & 7) * 16;

    // wait for superstep 0's rows, then prefetch
    wait_rows(cnt, 0);
    {
        const float* src = gi;
        for (int mm = 0; mm < 12; ++mm) {
            int off = (w * 12 + mm) * 256;
            async_copy16(src + off + (l << 2), smem + off * 4);
        }
    }

    for (int sb = 0; sb < NSB; ++sb) {
        int cb = sb & 1;
        u16x8 h0 = 0, h1 = 0;
        int hcopy = 0;
        if (sb > 0) {
            h0 = *(const u16x8*)(hist + fr * D + fc);
            h1 = *(const u16x8*)(hist + fr * D + fc + 8);
            if (t < 64) hcopy = ((const int*)(hist + SB * D))[t];
        }
        // prefetch sb+1 FIRST (so the counted vmcnt below can leave stores in flight)
        if (sb + 1 < NSB) {
            wait_rows(cnt, sb + 1);
            const float* src = gi + (size_t)(sb + 1) * SB * 3 * D;
            char* dst = smem + (cb ^ 1) * SB * 3 * D * 4;
            for (int mm = 0; mm < 12; ++mm) {
                int off = (w * 12 + mm) * 256;
                async_copy16(src + off + (l << 2), dst + off * 4);
            }
        }
        // output stores for superstep sb-1 (values already in regs; never need draining)
        if (sb > 0) {
            int orow = (sb - 1) * SB + fr - 1;
            if (isbf) {
                *(u16x8*)((unsigned short*)out + orow * D + fc) = h0;
                *(u16x8*)((unsigned short*)out + orow * D + fc + 8) = h1;
            } else {
                float* op = (float*)out + orow * D + fc;
                fx4 f0, f1, f2, f3;
#pragma unroll
                for (int j = 0; j < 4; ++j) {
                    f0[j] = bfbits2f(h0[j]);     f1[j] = bfbits2f(h0[4 + j]);
                    f2[j] = bfbits2f(h1[j]);     f3[j] = bfbits2f(h1[4 + j]);
                }
                *(fx4*)op = f0; *(fx4*)(op + 4) = f1;
                *(fx4*)(op + 8) = f2; *(fx4*)(op + 12) = f3;
            }
        }
        if (t < 64) ((int*)hist)[t] = (sb == 0) ? 0 : hcopy;

        // Counted vmcnt: in-order retirement => prefetch(sb) [issued at boundary sb-1] is
        // retired once outstanding <= (#vmem insts issued after it):
        //   sb==0: pf(1)=12                      -> vmcnt(12)
        //   sb==1: pf(2)+st(sb0 out: ns>=2)=14   -> vmcnt(14)
        //   mid:   st(ns)+pf(12)+st(ns)>=16      -> vmcnt(16)
        //   last:  st(ns)+st(ns)>=4              -> vmcnt(4)
        if (sb == 0)
            asm volatile("s_waitcnt vmcnt(12) lgkmcnt(0)\ns_barrier" ::: "memory");
        else if (sb == 1)
            asm volatile("s_waitcnt vmcnt(14) lgkmcnt(0)\ns_barrier" ::: "memory");
        else if (sb + 1 < NSB)
            asm volatile("s_waitcnt vmcnt(16) lgkmcnt(0)\ns_barrier" ::: "memory");
        else
            asm volatile("s_waitcnt vmcnt(4) lgkmcnt(0)\ns_barrier" ::: "memory");

        // running pointers for the inner loop
        const char* hrd = (const char*)hist + 16 * qq;            // step +256 B (one row)
        const float* gp = gi_lds + cb * SB * 3 * D + drow;        // step +384 floats
        short* hwr = hist + D + drow;                             // step +128 shorts

        for (int s = 0; s < SB; ++s) {
            bfx8 b0 = *(const bfx8*)(hrd);
            bfx8 b1 = *(const bfx8*)(hrd + 64);
            bfx8 b2 = *(const bfx8*)(hrd + 128);
            bfx8 b3 = *(const bfx8*)(hrd + 192);
            float gr = gp[0];
            float gz = gp[D];
            float gn = gp[2 * D];

            // 6 independent accumulate chains, interleaved by the scheduler (4-deep each);
            // DO NOT group by gate — grouping serializes the MFMA phase (round-1 regression).
            fx4 acc[3][2];
#pragma unroll
            for (int tau = 0; tau < 3; ++tau)
#pragma unroll
                for (int mqi = 0; mqi < 2; ++mqi) {
                    fx4 c = bias[tau][mqi];
                    c = MFMA(a[tau][mqi][0], b0, c);
                    c = MFMA(a[tau][mqi][1], b1, c);
                    c = MFMA(a[tau][mqi][2], b2, c);
                    c = MFMA(a[tau][mqi][3], b3, c);
                    acc[tau][mqi] = c;
                }

            float ar = sel4(mqsel ? acc[0][1] : acc[0][0], rsel);
            float az = sel4(mqsel ? acc[1][1] : acc[1][0], rsel);
            float an = sel4(mqsel ? acc[2][1] : acc[2][0], rsel);
            float rr = fast_sigmoid(gr + ar);
            float zz = fast_sigmoid(gz + az);
            float nst = fast_tanh(gn + rr * an);
            h = (1.f - zz) * nst + zz * h;
            *hwr = f2bf_bits(h);     // 2 replica lanes, same addr+data: free

            hrd += 256;
            gp += 3 * D;
            hwr += D;
            asm volatile("s_waitcnt lgkmcnt(0)\ns_barrier" ::: "memory");
        }
    }
    // final flush
    {
        u16x8 h0 = *(const u16x8*)(hist + fr * D + fc);
        u16x8 h1 = *(const u16x8*)(hist + fr * D + fc + 8);
        int orow = (NSB - 1) * SB + fr - 1;
        if (isbf) {
            *(u16x8*)((unsigned short*)out + orow * D + fc) = h0;
            *(u16x8*)((unsigned short*)out + orow * D + fc + 8) = h1;
        } else {
            float* op = (float*)out + orow * D + fc;
            fx4 f0, f1, f2, f3;
#pragma unroll
            for (int j = 0; j < 4; ++j) {
                f0[j] = bfbits2f(h0[j]);     f1[j] = bfbits2f(h0[4 + j]);
                f2[j] = bfbits2f(h1[j]);     f3[j] = bfbits2f(h1[4 + j]);
            }
            *(fx4*)op = f0; *(fx4*)(op + 4) = f1;
            *(fx4*)(op + 8) = f2; *(fx4*)(op + 12) = f3;
        }
    }
}

extern "C" void kernel_launch(void* const* d_in, const int* in_sizes, int n_in,
                              void* d_out, int out_size, void* d_ws, size_t ws_size,
                              hipStream_t stream) {
    (void)in_sizes; (void)n_in; (void)out_size; (void)ws_size;

    float* w0 = (float*)d_ws;
    int*   flag = (int*)w0;                 // w0[0]
    int*   cnt  = (int*)w0 + 16;            // w0[16..48): per-superstep row counters
    float* Xf   = w0 + 64;
    float* Wqf  = Xf   + N * D;
    float* Wkf  = Wqf  + D * D;
    float* vf   = Wkf  + D * D;
    float* wihf = vf   + D;
    float* whhf = wihf + 3 * D * 2 * D;
    float* bihf = whhf + 3 * D * D;
    float* bhhf = bihf + 3 * D;
    float* q    = bhhf + 3 * D;
    float* kT   = q    + N * D;
    float* wihT = kT   + N * D;             // 3D x 2D transposed
    float* WqT  = wihT + 3 * D * 2 * D;     // D x D transposed
    float* WkT  = WqT  + D * D;
    float* gi   = WkT  + D * D;             // N x 3D

    sniff_kernel<<<1, 64, 0, stream>>>((const unsigned short*)d_in[0], flag, cnt);

    ConvArgs A;
    A.p[0] = d_in[0]; A.o[0] = Xf;   A.n[0] = N * D;
    A.p[1] = d_in[1]; A.o[1] = Wqf;  A.n[1] = D * D;
    A.p[2] = d_in[2]; A.o[2] = Wkf;  A.n[2] = D * D;
    A.p[3] = d_in[3]; A.o[3] = vf;   A.n[3] = D;
    A.p[4] = d_in[4]; A.o[4] = wihf; A.n[4] = 3 * D * 2 * D;
    A.p[5] = d_in[5]; A.o[5] = whhf; A.n[5] = 3 * D * D;
    A.p[6] = d_in[6]; A.o[6] = bihf; A.n[6] = 3 * D;
    A.p[7] = d_in[7]; A.o[7] = bhhf; A.n[7] = 3 * D;
    dim3 cgrid(128, 8, 1);
    convert_kernel<<<cgrid, 256, 0, stream>>>(A, flag);

    transpose_all<<<(3 * D * 2 * D + 2 * D * D) / 256, 256, 0, stream>>>(
        wihf, wihT, Wqf, WqT, Wkf, WkT);
    qk_kernel<<<N, 256, 0, stream>>>(Xf, WqT, WkT, q, kT);
    fused_kernel<<<N + 1, 256, 0, stream>>>(q, kT, vf, Xf, wihT, bihf, gi,
                                            whhf, bhhf, d_out, flag, cnt);
}